// Round 17
// baseline (271.367 us; speedup 1.0000x reference)
//
#include <hip/hip_runtime.h>

#define N_NODES   100000
#define N_EDGES   1600000
#define N_GRAPHS  128
#define HIDDEN    128
#define N_CLASSES 10

#define BSH   9                   // bucket = 512 nodes (partition-friendly)
#define BSZ   512
#define NBUCK 196                 // ceil(100000/512)
#define CAP   16384               // mean fill 8192, sigma ~90
#define PCH   4096                // edges per partition block
#define PTH   512                 // partition threads
#define PIT   (PCH / PTH)         // 8 edges cached per thread

typedef unsigned int   uint;
typedef unsigned short ushort;
typedef unsigned char  uchar;

// -------- partition, two sequential phases sharing one staging buffer;
//          src/dst register-cached across phases (single global read of each).
__global__ __launch_bounds__(PTH)
void k_part(const int* __restrict__ src, const int* __restrict__ dst,
            unsigned* __restrict__ bcur1, unsigned* __restrict__ bcur2,
            unsigned* __restrict__ tmp1, ushort* __restrict__ tmp2, int nE) {
    __shared__ unsigned hist[256], scanT[256], lcur[256], base[256];
    __shared__ unsigned stag4[PCH];      // 16 KB
    __shared__ uchar    stagB[PCH];      // 4 KB (phase 1 only)
    int t = threadIdx.x;
    int e0 = blockIdx.x * PCH;
    int e1 = min(e0 + PCH, nE);
    int cntE = e1 - e0;

    int sv[PIT], dv[PIT];
    // ---------------- phase 1: dst ----------------
    if (t < 256) hist[t] = 0;
    __syncthreads();
    #pragma unroll
    for (int m = 0; m < PIT; ++m) {
        int e = e0 + t + m * PTH;
        if (e < e1) {
            sv[m] = src[e]; dv[m] = dst[e];
            atomicAdd(&hist[dv[m] >> BSH], 1u);
        }
    }
    __syncthreads();
    unsigned v = (t < 256) ? hist[t] : 0u;
    if (t < 256) scanT[t] = v;
    __syncthreads();
    for (int off = 1; off < 256; off <<= 1) {
        unsigned add = (t < 256 && t >= off) ? scanT[t - off] : 0u;
        __syncthreads();
        if (t < 256) scanT[t] += add;
        __syncthreads();
    }
    if (t < 256) {
        unsigned excl = scanT[t] - v;
        lcur[t] = excl;
        if (v > 0) { unsigned g = atomicAdd(&bcur1[t], v); base[t] = (unsigned)t * CAP + g - excl; }
    }
    __syncthreads();
    #pragma unroll
    for (int m = 0; m < PIT; ++m) {
        int e = e0 + t + m * PTH;
        if (e < e1) {
            int d = dv[m], s = sv[m];
            int b = d >> BSH;
            unsigned p = atomicAdd(&lcur[b], 1u);
            stag4[p] = ((unsigned)(d & (BSZ - 1)) << 17) | (unsigned)s;
            stagB[p] = (uchar)b;
        }
    }
    __syncthreads();
    for (int i = t; i < cntE; i += PTH) {
        unsigned b = stagB[i];
        unsigned a = base[b] + (unsigned)i;
        if (a < (b + 1u) * CAP) tmp1[a] = stag4[i];
    }
    __syncthreads();

    // ---------------- phase 2: src (stage full src; bucket re-derived) ----------------
    if (t < 256) hist[t] = 0;
    __syncthreads();
    #pragma unroll
    for (int m = 0; m < PIT; ++m) {
        int e = e0 + t + m * PTH;
        if (e < e1) atomicAdd(&hist[sv[m] >> BSH], 1u);
    }
    __syncthreads();
    v = (t < 256) ? hist[t] : 0u;
    if (t < 256) scanT[t] = v;
    __syncthreads();
    for (int off = 1; off < 256; off <<= 1) {
        unsigned add = (t < 256 && t >= off) ? scanT[t - off] : 0u;
        __syncthreads();
        if (t < 256) scanT[t] += add;
        __syncthreads();
    }
    if (t < 256) {
        unsigned excl = scanT[t] - v;
        lcur[t] = excl;
        if (v > 0) { unsigned g = atomicAdd(&bcur2[t], v); base[t] = (unsigned)t * CAP + g - excl; }
    }
    __syncthreads();
    #pragma unroll
    for (int m = 0; m < PIT; ++m) {
        int e = e0 + t + m * PTH;
        if (e < e1) {
            int s = sv[m];
            unsigned p = atomicAdd(&lcur[s >> BSH], 1u);
            stag4[p] = (unsigned)s;
        }
    }
    __syncthreads();
    for (int i = t; i < cntE; i += PTH) {
        unsigned s = stag4[i];
        unsigned b = s >> BSH;
        unsigned a = base[b] + (unsigned)i;
        if (a < (b + 1u) * CAP) tmp2[a] = (ushort)(s & (BSZ - 1));
    }
}

// ------- per bucket (1024 thr): degrees + ns + hs0 + bucket counting-sort → CSR
//         rsind[n] = (csr_row_start << 10) | indeg
__global__ __launch_bounds__(1024)
void k_ind_csr(const unsigned* __restrict__ bcur1, const unsigned* __restrict__ tmp1,
               const unsigned* __restrict__ bcur2, const ushort* __restrict__ tmp2,
               unsigned* __restrict__ rsind, float* __restrict__ ns,
               float* __restrict__ hs0, int* __restrict__ csr) {
    __shared__ unsigned cin[BSZ], cout[BSZ], pref[BSZ], lcur[BSZ];
    int b = blockIdx.x, t = threadIdx.x;
    if (t < BSZ) { cin[t] = 0; cout[t] = 0; }
    __syncthreads();
    unsigned f1 = min(bcur1[b], (unsigned)CAP);
    const unsigned* tp1 = tmp1 + (size_t)b * CAP;
    for (unsigned i = t; i < f1; i += 1024) atomicAdd(&cin[tp1[i] >> 17], 1u);
    unsigned f2 = min(bcur2[b], (unsigned)CAP);
    const ushort* tp2 = tmp2 + (size_t)b * CAP;
    for (unsigned i = t; i < f2; i += 1024) atomicAdd(&cout[tp2[i]], 1u);
    __syncthreads();
    unsigned v = (t < BSZ) ? cin[t] : 0u;
    if (t < BSZ) pref[t] = v;
    __syncthreads();
    for (int off = 1; off < BSZ; off <<= 1) {
        unsigned add = (t < BSZ && t >= off) ? pref[t - off] : 0u;
        __syncthreads();
        if (t < BSZ) pref[t] += add;
        __syncthreads();
    }
    if (t < BSZ) {
        unsigned excl = pref[t] - v;
        lcur[t] = excl;
        int n = b * BSZ + t;
        if (n < N_NODES) {
            unsigned co = cout[t];
            float nsv = rsqrtf(fmaxf((float)co, 1.0f));
            ns[n]    = nsv;
            hs0[n]   = (float)v * nsv;
            rsind[n] = (((unsigned)b * CAP + excl) << 10) | min(v, 1023u);
        }
    }
    __syncthreads();
    int* cb = csr + (size_t)b * CAP;
    for (unsigned i = t; i < f1; i += 1024) {
        unsigned e = tp1[i];
        unsigned pos = atomicAdd(&lcur[e >> 17], 1u);
        cb[pos] = (int)(e & 0x1FFFFu);
    }
}

// ---- conv1: 2 threads/node CSR gather + node info (c, ns, seg, nd).
//      Segment id counted against UNSORTED breakpoints (order-independent).
//      Blocks 0..128 sort + emit U/V rows with UNCONDITIONAL W2 loads (ILP).
__global__ __launch_bounds__(256)
void k_conv1_info(const unsigned* __restrict__ rsind, const int* __restrict__ csr,
                  const float* __restrict__ hs0, const float* __restrict__ ns,
                  const float* __restrict__ W1, const float* __restrict__ b1,
                  const float* __restrict__ W2,
                  float* __restrict__ U, float* __restrict__ V,
                  float4* __restrict__ info, int nN) {
    __shared__ float stu[128];        // unsorted breakpoints
    __shared__ float sts[128];        // sorted (only blocks < 129)
    int t = threadIdx.x;
    if (t < 128) {
        float w = W1[t], bb = b1[t];
        stu[t] = (w != 0.0f) ? (-bb / w) : 1e30f;
    }
    __syncthreads();
    if (blockIdx.x < 129) {           // block-uniform branch: syncs are legal
        if (t < 128) sts[t] = stu[t];
        __syncthreads();
        for (int k = 2; k <= 128; k <<= 1) {
            for (int j = k >> 1; j > 0; j >>= 1) {
                if (t < 128) {
                    int ixj = t ^ j;
                    if (ixj > t) {
                        float a = sts[t], bb = sts[ixj];
                        bool up = ((t & k) == 0);
                        if (up ? (a > bb) : (a < bb)) { sts[t] = bb; sts[ixj] = a; }
                    }
                }
                __syncthreads();
            }
        }
        if (t < 128) {                // segment-table row, unconditional loads
            int sg = blockIdx.x;
            float a_rep;
            if (sg == 0)        a_rep = sts[0]   - 1.0f;
            else if (sg == 128) a_rep = sts[127] + 1.0f;
            else                a_rep = 0.5f * (sts[sg - 1] + sts[sg]);
            float u = 0.0f, vv = 0.0f;
            #pragma unroll 8
            for (int j = 0; j < 128; ++j) {
                float w  = W1[j], bb = b1[j];
                float w2 = W2[j * HIDDEN + t];          // always load → pipelined
                bool on  = (a_rep * w + bb > 0.0f);
                u  += on ? w  * w2 : 0.0f;
                vv += on ? bb * w2 : 0.0f;
            }
            U[sg * HIDDEN + t] = u;
            V[sg * HIDDEN + t] = vv;
        }
    }
    // per-node info: 2 threads per node, unsorted count
    int node = blockIdx.x * 128 + (t >> 1);
    if (node >= nN) return;
    int j  = t & 1;
    unsigned rix = rsind[node];
    int r0 = (int)(rix >> 10);
    int c  = (int)(rix & 1023u);
    float a = 0.0f;
    #pragma unroll 4
    for (int k = j; k < c; k += 2) a += hs0[csr[r0 + k]];
    a += __shfl_xor(a, 1);
    float nd = rsqrtf(fmaxf((float)c, 1.0f));
    float av = a * nd;
    int sgp = 0;
    #pragma unroll
    for (int q = 0; q < 64; ++q) sgp += (stu[j * 64 + q] < av) ? 1 : 0;
    sgp += __shfl_xor(sgp, 1);
    if (j == 0) {
        float nsv = ns[node];
        info[node] = make_float4(nsv * av, nsv, __int_as_float(sgp), nd);
    }
}

// ---- conv2: 4 threads/node register gather; 4 waves compute relu rows → LDS;
//      wave 0 pools; LAST block (device ticket) computes the classifier head.
__global__ __launch_bounds__(256)
void k_conv2_pool(const unsigned* __restrict__ rsind, const int* __restrict__ csr,
                  const float4* __restrict__ info,
                  const float* __restrict__ U, const float* __restrict__ V,
                  const int* __restrict__ graph_ids, const float* __restrict__ b2,
                  const float* __restrict__ Wc, const float* __restrict__ bc,
                  float* __restrict__ pool, float* __restrict__ cnt,
                  unsigned* __restrict__ done, float* __restrict__ out, int nN) {
    __shared__ float sA[64], sB[64], sND[64];
    __shared__ int   sSg[64], sGr[64], sR[64], sC[64];
    __shared__ float sRes[64][HIDDEN];          // 32 KB relu'd rows
    __shared__ unsigned sTicket;
    int blockBase = blockIdx.x * 64;
    int t = threadIdx.x;
    int node = blockBase + (t >> 2);
    int j = t & 3;

    float A = 0.0f, B = 0.0f;
    int mn = 255, mx = 0;
    int r0 = 0, c = 0;
    if (node < nN) {
        unsigned rix = rsind[node];
        r0 = (int)(rix >> 10); c = (int)(rix & 1023u);
        #pragma unroll 4
        for (int k = j; k < c; k += 4) {
            float4 nf = info[csr[r0 + k]];
            int sg = __float_as_int(nf.z);
            A += nf.x; B += nf.y;
            mn = min(mn, sg); mx = max(mx, sg);
        }
    }
    A += __shfl_xor(A, 1); A += __shfl_xor(A, 2);
    B += __shfl_xor(B, 1); B += __shfl_xor(B, 2);
    mn = min(mn, __shfl_xor(mn, 1)); mn = min(mn, __shfl_xor(mn, 2));
    mx = max(mx, __shfl_xor(mx, 1)); mx = max(mx, __shfl_xor(mx, 2));
    if (node < nN && j == 0) {
        int i = t >> 2;
        sA[i] = A; sB[i] = B;
        sSg[i] = (mn << 8) | mx;
        sR[i] = r0; sC[i] = c;
        sND[i] = info[node].w;
        sGr[i] = graph_ids[node];
    }
    __syncthreads();

    // phase 2a: all 4 waves compute relu rows (16 nodes each) → LDS
    int w = t >> 6, lane = t & 63;
    float bb0 = b2[lane], bb1 = b2[64 + lane];
    for (int i = w * 16; i < w * 16 + 16; ++i) {
        int n = blockBase + i;
        if (n >= nN) break;
        int pk = sSg[i], smn = pk >> 8, smx = pk & 255;
        float acc0, acc1;
        if (smn >= smx) {                      // uniform segment (or no edges)
            int sg = min(smn, 128);
            float Av = sA[i], Bv = sB[i];
            const float* Ur = U + sg * HIDDEN;
            const float* Vr = V + sg * HIDDEN;
            acc0 = Av * Ur[lane]      + Bv * Vr[lane];
            acc1 = Av * Ur[64 + lane] + Bv * Vr[64 + lane];
        } else {                               // mixed: exact per-node rescan (rare)
            acc0 = 0.0f; acc1 = 0.0f;
            int rr = sR[i], cc = sC[i];
            for (int k = 0; k < cc; ++k) {
                float4 nf = info[csr[rr + k]];
                int sg = __float_as_int(nf.z);
                const float* Ur = U + sg * HIDDEN;
                const float* Vr = V + sg * HIDDEN;
                acc0 += nf.x * Ur[lane]      + nf.y * Vr[lane];
                acc1 += nf.x * Ur[64 + lane] + nf.y * Vr[64 + lane];
            }
        }
        float nd = sND[i];
        sRes[i][lane]      = fmaxf(nd * acc0 + bb0, 0.0f);
        sRes[i][64 + lane] = fmaxf(nd * acc1 + bb1, 0.0f);
    }
    __syncthreads();

    // phase 2b: wave 0 pools from LDS (sorted graph_ids → few flushes)
    if (t < 64) {
        int lane0 = t;
        int gcur = -1;
        float racc0 = 0.0f, racc1 = 0.0f, cl = 0.0f;
        for (int i = 0; i < 64; ++i) {
            int n = blockBase + i;
            if (n >= nN) break;
            float r0v = sRes[i][lane0];
            float r1v = sRes[i][64 + lane0];
            int g = sGr[i];
            if (g != gcur) {
                if (gcur >= 0) {
                    atomicAdd(&pool[gcur * HIDDEN + lane0],      racc0);
                    atomicAdd(&pool[gcur * HIDDEN + 64 + lane0], racc1);
                    if (lane0 == 0) atomicAdd(&cnt[gcur], cl);
                }
                gcur = g; racc0 = 0.0f; racc1 = 0.0f; cl = 0.0f;
            }
            racc0 += r0v; racc1 += r1v; cl += 1.0f;
        }
        if (gcur >= 0) {
            atomicAdd(&pool[gcur * HIDDEN + lane0],      racc0);
            atomicAdd(&pool[gcur * HIDDEN + 64 + lane0], racc1);
            if (lane0 == 0) atomicAdd(&cnt[gcur], cl);
        }
    }

    // ---- last-block ticket → classifier head (atomic reads: XCD-coherent)
    __threadfence();
    __syncthreads();
    if (t == 0) sTicket = atomicAdd(done, 1u);
    __syncthreads();
    if (sTicket != (unsigned)gridDim.x - 1) return;
    if (t < N_GRAPHS) {
        int g = t;
        float cv = atomicAdd(&cnt[g], 0.0f);
        float inv = 1.0f / fmaxf(cv, 1.0f);
        float acc[N_CLASSES];
        #pragma unroll
        for (int c2 = 0; c2 < N_CLASSES; ++c2) acc[c2] = bc[c2];
        for (int j2 = 0; j2 < HIDDEN; ++j2) {
            float pv = atomicAdd(&pool[g * HIDDEN + j2], 0.0f) * inv;
            #pragma unroll
            for (int c2 = 0; c2 < N_CLASSES; ++c2) acc[c2] += pv * Wc[j2 * N_CLASSES + c2];
        }
        #pragma unroll
        for (int c2 = 0; c2 < N_CLASSES; ++c2) out[g * N_CLASSES + c2] = acc[c2];
    }
}

extern "C" void kernel_launch(void* const* d_in, const int* in_sizes, int n_in,
                              void* d_out, int out_size, void* d_ws, size_t ws_size,
                              hipStream_t stream) {
    const int*   src       = (const int*)d_in[0];
    const int*   dst       = (const int*)d_in[1];
    const int*   graph_ids = (const int*)d_in[2];
    const float* W1        = (const float*)d_in[3];
    const float* b1        = (const float*)d_in[4];
    const float* W2        = (const float*)d_in[5];
    const float* b2        = (const float*)d_in[6];
    const float* Wc        = (const float*)d_in[7];
    const float* bc        = (const float*)d_in[8];
    float* out = (float*)d_out;

    char* ws = (char*)d_ws;
    size_t off = 0;
    auto alloc = [&](size_t elems) { void* p = ws + off; off += elems * 4; return p; };

    // --- zeroed region (one tiny memset, 16B-multiple) ---
    unsigned* bcur1 = (unsigned*)alloc(256);
    unsigned* bcur2 = (unsigned*)alloc(256);
    float*    pool  = (float*)   alloc(N_GRAPHS * HIDDEN);
    float*    cnt   = (float*)   alloc(N_GRAPHS);
    unsigned* done  = (unsigned*)alloc(4);           // +pad keeps 16B alignment
    size_t zero_bytes = off;
    // --- non-zeroed ---
    float4*   info  = (float4*)  alloc((size_t)N_NODES * 4);        // 1.6 MB
    unsigned* tmp1  = (unsigned*)alloc((size_t)NBUCK * CAP);        // 12.8 MB
    ushort*   tmp2  = (ushort*)  alloc((size_t)NBUCK * CAP / 2);    // 6.4 MB
    int*      csr   = (int*)     alloc((size_t)NBUCK * CAP);        // 12.8 MB
    unsigned* rsind = (unsigned*)alloc(N_NODES);
    float*    nsA   = (float*)   alloc(N_NODES);
    float*    hs0   = (float*)   alloc(N_NODES);
    float*    U     = (float*)   alloc(129 * HIDDEN);
    float*    V     = (float*)   alloc(129 * HIDDEN);

    hipMemsetAsync(d_ws, 0, zero_bytes, stream);

    int pblocks  = (N_EDGES + PCH - 1) / PCH;    // 391
    int c1blocks = (N_NODES + 127) / 128;        // 782
    int c2blocks = (N_NODES + 63) / 64;          // 1563
    k_part      <<<pblocks, PTH, 0, stream>>>(src, dst, bcur1, bcur2, tmp1, tmp2, N_EDGES);
    k_ind_csr   <<<NBUCK, 1024, 0, stream>>>(bcur1, tmp1, bcur2, tmp2, rsind, nsA, hs0, csr);
    k_conv1_info<<<c1blocks, 256, 0, stream>>>(rsind, csr, hs0, nsA, W1, b1, W2, U, V, info, N_NODES);
    k_conv2_pool<<<c2blocks, 256, 0, stream>>>(rsind, csr, info, U, V, graph_ids, b2, Wc, bc, pool, cnt, done, out, N_NODES);
}

// Round 18
// 170.235 us; speedup vs baseline: 1.5941x; 1.5941x over previous
//
#include <hip/hip_runtime.h>

#define N_NODES   100000
#define N_EDGES   1600000
#define N_GRAPHS  128
#define HIDDEN    128
#define N_CLASSES 10

#define BSH   9                   // bucket = 512 nodes (partition-friendly)
#define BSZ   512
#define NBUCK 196                 // ceil(100000/512)
#define CAP   16384               // mean fill 8192, sigma ~90
#define PCH   4096                // edges per partition block
#define PTH   512                 // partition threads
#define PIT   (PCH / PTH)         // 8 edges cached per thread

typedef unsigned int   uint;
typedef unsigned short ushort;
typedef unsigned char  uchar;

// -------- partition, two sequential phases sharing one staging buffer;
//          src/dst register-cached across phases (single global read of each).
__global__ __launch_bounds__(PTH)
void k_part(const int* __restrict__ src, const int* __restrict__ dst,
            unsigned* __restrict__ bcur1, unsigned* __restrict__ bcur2,
            unsigned* __restrict__ tmp1, ushort* __restrict__ tmp2, int nE) {
    __shared__ unsigned hist[256], scanT[256], lcur[256], base[256];
    __shared__ unsigned stag4[PCH];      // 16 KB
    __shared__ uchar    stagB[PCH];      // 4 KB (phase 1 only)
    int t = threadIdx.x;
    int e0 = blockIdx.x * PCH;
    int e1 = min(e0 + PCH, nE);
    int cntE = e1 - e0;

    int sv[PIT], dv[PIT];
    // ---------------- phase 1: dst ----------------
    if (t < 256) hist[t] = 0;
    __syncthreads();
    #pragma unroll
    for (int m = 0; m < PIT; ++m) {
        int e = e0 + t + m * PTH;
        if (e < e1) {
            sv[m] = src[e]; dv[m] = dst[e];
            atomicAdd(&hist[dv[m] >> BSH], 1u);
        }
    }
    __syncthreads();
    unsigned v = (t < 256) ? hist[t] : 0u;
    if (t < 256) scanT[t] = v;
    __syncthreads();
    for (int off = 1; off < 256; off <<= 1) {
        unsigned add = (t < 256 && t >= off) ? scanT[t - off] : 0u;
        __syncthreads();
        if (t < 256) scanT[t] += add;
        __syncthreads();
    }
    if (t < 256) {
        unsigned excl = scanT[t] - v;
        lcur[t] = excl;
        if (v > 0) { unsigned g = atomicAdd(&bcur1[t], v); base[t] = (unsigned)t * CAP + g - excl; }
    }
    __syncthreads();
    #pragma unroll
    for (int m = 0; m < PIT; ++m) {
        int e = e0 + t + m * PTH;
        if (e < e1) {
            int d = dv[m], s = sv[m];
            int b = d >> BSH;
            unsigned p = atomicAdd(&lcur[b], 1u);
            stag4[p] = ((unsigned)(d & (BSZ - 1)) << 17) | (unsigned)s;
            stagB[p] = (uchar)b;
        }
    }
    __syncthreads();
    for (int i = t; i < cntE; i += PTH) {
        unsigned b = stagB[i];
        unsigned a = base[b] + (unsigned)i;
        if (a < (b + 1u) * CAP) tmp1[a] = stag4[i];
    }
    __syncthreads();

    // ---------------- phase 2: src (stage full src; bucket re-derived) ----------------
    if (t < 256) hist[t] = 0;
    __syncthreads();
    #pragma unroll
    for (int m = 0; m < PIT; ++m) {
        int e = e0 + t + m * PTH;
        if (e < e1) atomicAdd(&hist[sv[m] >> BSH], 1u);
    }
    __syncthreads();
    v = (t < 256) ? hist[t] : 0u;
    if (t < 256) scanT[t] = v;
    __syncthreads();
    for (int off = 1; off < 256; off <<= 1) {
        unsigned add = (t < 256 && t >= off) ? scanT[t - off] : 0u;
        __syncthreads();
        if (t < 256) scanT[t] += add;
        __syncthreads();
    }
    if (t < 256) {
        unsigned excl = scanT[t] - v;
        lcur[t] = excl;
        if (v > 0) { unsigned g = atomicAdd(&bcur2[t], v); base[t] = (unsigned)t * CAP + g - excl; }
    }
    __syncthreads();
    #pragma unroll
    for (int m = 0; m < PIT; ++m) {
        int e = e0 + t + m * PTH;
        if (e < e1) {
            int s = sv[m];
            unsigned p = atomicAdd(&lcur[s >> BSH], 1u);
            stag4[p] = (unsigned)s;
        }
    }
    __syncthreads();
    for (int i = t; i < cntE; i += PTH) {
        unsigned s = stag4[i];
        unsigned b = s >> BSH;
        unsigned a = base[b] + (unsigned)i;
        if (a < (b + 1u) * CAP) tmp2[a] = (ushort)(s & (BSZ - 1));
    }
}

// ------- per bucket (1024 thr): degrees + ns + hs0 + bucket counting-sort → CSR
//         rsind[n] = (csr_row_start << 10) | indeg
__global__ __launch_bounds__(1024)
void k_ind_csr(const unsigned* __restrict__ bcur1, const unsigned* __restrict__ tmp1,
               const unsigned* __restrict__ bcur2, const ushort* __restrict__ tmp2,
               unsigned* __restrict__ rsind, float* __restrict__ ns,
               float* __restrict__ hs0, int* __restrict__ csr) {
    __shared__ unsigned cin[BSZ], cout[BSZ], pref[BSZ], lcur[BSZ];
    int b = blockIdx.x, t = threadIdx.x;
    if (t < BSZ) { cin[t] = 0; cout[t] = 0; }
    __syncthreads();
    unsigned f1 = min(bcur1[b], (unsigned)CAP);
    const unsigned* tp1 = tmp1 + (size_t)b * CAP;
    for (unsigned i = t; i < f1; i += 1024) atomicAdd(&cin[tp1[i] >> 17], 1u);
    unsigned f2 = min(bcur2[b], (unsigned)CAP);
    const ushort* tp2 = tmp2 + (size_t)b * CAP;
    for (unsigned i = t; i < f2; i += 1024) atomicAdd(&cout[tp2[i]], 1u);
    __syncthreads();
    unsigned v = (t < BSZ) ? cin[t] : 0u;
    if (t < BSZ) pref[t] = v;
    __syncthreads();
    for (int off = 1; off < BSZ; off <<= 1) {
        unsigned add = (t < BSZ && t >= off) ? pref[t - off] : 0u;
        __syncthreads();
        if (t < BSZ) pref[t] += add;
        __syncthreads();
    }
    if (t < BSZ) {
        unsigned excl = pref[t] - v;
        lcur[t] = excl;
        int n = b * BSZ + t;
        if (n < N_NODES) {
            unsigned co = cout[t];
            float nsv = rsqrtf(fmaxf((float)co, 1.0f));
            ns[n]    = nsv;
            hs0[n]   = (float)v * nsv;
            rsind[n] = (((unsigned)b * CAP + excl) << 10) | min(v, 1023u);
        }
    }
    __syncthreads();
    int* cb = csr + (size_t)b * CAP;
    for (unsigned i = t; i < f1; i += 1024) {
        unsigned e = tp1[i];
        unsigned pos = atomicAdd(&lcur[e >> 17], 1u);
        cb[pos] = (int)(e & 0x1FFFFu);
    }
}

// ---- conv1: 2 threads/node CSR gather + node info (c, ns, seg, nd).
//      Segment id counted against UNSORTED breakpoints (order-independent).
//      Blocks 0..128 sort + emit U/V rows with UNCONDITIONAL W2 loads (ILP).
__global__ __launch_bounds__(256)
void k_conv1_info(const unsigned* __restrict__ rsind, const int* __restrict__ csr,
                  const float* __restrict__ hs0, const float* __restrict__ ns,
                  const float* __restrict__ W1, const float* __restrict__ b1,
                  const float* __restrict__ W2,
                  float* __restrict__ U, float* __restrict__ V,
                  float4* __restrict__ info, int nN) {
    __shared__ float stu[128];        // unsorted breakpoints
    __shared__ float sts[128];        // sorted (only blocks < 129)
    int t = threadIdx.x;
    if (t < 128) {
        float w = W1[t], bb = b1[t];
        stu[t] = (w != 0.0f) ? (-bb / w) : 1e30f;
    }
    __syncthreads();
    if (blockIdx.x < 129) {           // block-uniform branch: syncs are legal
        if (t < 128) sts[t] = stu[t];
        __syncthreads();
        for (int k = 2; k <= 128; k <<= 1) {
            for (int j = k >> 1; j > 0; j >>= 1) {
                if (t < 128) {
                    int ixj = t ^ j;
                    if (ixj > t) {
                        float a = sts[t], bb = sts[ixj];
                        bool up = ((t & k) == 0);
                        if (up ? (a > bb) : (a < bb)) { sts[t] = bb; sts[ixj] = a; }
                    }
                }
                __syncthreads();
            }
        }
        if (t < 128) {                // segment-table row, unconditional loads
            int sg = blockIdx.x;
            float a_rep;
            if (sg == 0)        a_rep = sts[0]   - 1.0f;
            else if (sg == 128) a_rep = sts[127] + 1.0f;
            else                a_rep = 0.5f * (sts[sg - 1] + sts[sg]);
            float u = 0.0f, vv = 0.0f;
            #pragma unroll 8
            for (int j = 0; j < 128; ++j) {
                float w  = W1[j], bb = b1[j];
                float w2 = W2[j * HIDDEN + t];          // always load → pipelined
                bool on  = (a_rep * w + bb > 0.0f);
                u  += on ? w  * w2 : 0.0f;
                vv += on ? bb * w2 : 0.0f;
            }
            U[sg * HIDDEN + t] = u;
            V[sg * HIDDEN + t] = vv;
        }
    }
    // per-node info: 2 threads per node, unsorted count
    int node = blockIdx.x * 128 + (t >> 1);
    if (node >= nN) return;
    int j  = t & 1;
    unsigned rix = rsind[node];
    int r0 = (int)(rix >> 10);
    int c  = (int)(rix & 1023u);
    float a = 0.0f;
    #pragma unroll 4
    for (int k = j; k < c; k += 2) a += hs0[csr[r0 + k]];
    a += __shfl_xor(a, 1);
    float nd = rsqrtf(fmaxf((float)c, 1.0f));
    float av = a * nd;
    int sgp = 0;
    #pragma unroll
    for (int q = 0; q < 64; ++q) sgp += (stu[j * 64 + q] < av) ? 1 : 0;
    sgp += __shfl_xor(sgp, 1);
    if (j == 0) {
        float nsv = ns[node];
        info[node] = make_float4(nsv * av, nsv, __int_as_float(sgp), nd);
    }
}

// ---- conv2: 4 threads/node register gather (shuffle combine); then ALL 4 waves
//      compute relu rows (16 nodes each) into LDS; wave 0 pools from LDS.
__global__ __launch_bounds__(256)
void k_conv2_pool(const unsigned* __restrict__ rsind, const int* __restrict__ csr,
                  const float4* __restrict__ info,
                  const float* __restrict__ U, const float* __restrict__ V,
                  const int* __restrict__ graph_ids, const float* __restrict__ b2,
                  float* __restrict__ pool, float* __restrict__ cnt, int nN) {
    __shared__ float sA[64], sB[64], sND[64];
    __shared__ int   sSg[64], sGr[64], sR[64], sC[64];
    __shared__ float sRes[64][HIDDEN];          // 32 KB relu'd rows
    int blockBase = blockIdx.x * 64;
    int t = threadIdx.x;
    int node = blockBase + (t >> 2);
    int j = t & 3;

    float A = 0.0f, B = 0.0f;
    int mn = 255, mx = 0;
    int r0 = 0, c = 0;
    if (node < nN) {
        unsigned rix = rsind[node];
        r0 = (int)(rix >> 10); c = (int)(rix & 1023u);
        #pragma unroll 4
        for (int k = j; k < c; k += 4) {
            float4 nf = info[csr[r0 + k]];
            int sg = __float_as_int(nf.z);
            A += nf.x; B += nf.y;
            mn = min(mn, sg); mx = max(mx, sg);
        }
    }
    A += __shfl_xor(A, 1); A += __shfl_xor(A, 2);
    B += __shfl_xor(B, 1); B += __shfl_xor(B, 2);
    mn = min(mn, __shfl_xor(mn, 1)); mn = min(mn, __shfl_xor(mn, 2));
    mx = max(mx, __shfl_xor(mx, 1)); mx = max(mx, __shfl_xor(mx, 2));
    if (node < nN && j == 0) {
        int i = t >> 2;
        sA[i] = A; sB[i] = B;
        sSg[i] = (mn << 8) | mx;
        sR[i] = r0; sC[i] = c;
        sND[i] = info[node].w;
        sGr[i] = graph_ids[node];
    }
    __syncthreads();

    // phase 2a: all 4 waves compute relu rows (16 nodes each) → LDS
    int w = t >> 6, lane = t & 63;
    float bb0 = b2[lane], bb1 = b2[64 + lane];
    for (int i = w * 16; i < w * 16 + 16; ++i) {
        int n = blockBase + i;
        if (n >= nN) break;
        int pk = sSg[i], smn = pk >> 8, smx = pk & 255;
        float acc0, acc1;
        if (smn >= smx) {                      // uniform segment (or no edges)
            int sg = min(smn, 128);
            float Av = sA[i], Bv = sB[i];
            const float* Ur = U + sg * HIDDEN;
            const float* Vr = V + sg * HIDDEN;
            acc0 = Av * Ur[lane]      + Bv * Vr[lane];
            acc1 = Av * Ur[64 + lane] + Bv * Vr[64 + lane];
        } else {                               // mixed: exact per-node rescan (rare)
            acc0 = 0.0f; acc1 = 0.0f;
            int rr = sR[i], cc = sC[i];
            for (int k = 0; k < cc; ++k) {
                float4 nf = info[csr[rr + k]];
                int sg = __float_as_int(nf.z);
                const float* Ur = U + sg * HIDDEN;
                const float* Vr = V + sg * HIDDEN;
                acc0 += nf.x * Ur[lane]      + nf.y * Vr[lane];
                acc1 += nf.x * Ur[64 + lane] + nf.y * Vr[64 + lane];
            }
        }
        float nd = sND[i];
        sRes[i][lane]      = fmaxf(nd * acc0 + bb0, 0.0f);
        sRes[i][64 + lane] = fmaxf(nd * acc1 + bb1, 0.0f);
    }
    __syncthreads();

    // phase 2b: wave 0 pools from LDS (sorted graph_ids → few flushes)
    if (t >= 64) return;
    int lane0 = t;
    int gcur = -1;
    float racc0 = 0.0f, racc1 = 0.0f, cl = 0.0f;
    for (int i = 0; i < 64; ++i) {
        int n = blockBase + i;
        if (n >= nN) break;
        float r0v = sRes[i][lane0];
        float r1v = sRes[i][64 + lane0];
        int g = sGr[i];
        if (g != gcur) {
            if (gcur >= 0) {
                atomicAdd(&pool[gcur * HIDDEN + lane0],      racc0);
                atomicAdd(&pool[gcur * HIDDEN + 64 + lane0], racc1);
                if (lane0 == 0) atomicAdd(&cnt[gcur], cl);
            }
            gcur = g; racc0 = 0.0f; racc1 = 0.0f; cl = 0.0f;
        }
        racc0 += r0v; racc1 += r1v; cl += 1.0f;
    }
    if (gcur >= 0) {
        atomicAdd(&pool[gcur * HIDDEN + lane0],      racc0);
        atomicAdd(&pool[gcur * HIDDEN + 64 + lane0], racc1);
        if (lane0 == 0) atomicAdd(&cnt[gcur], cl);
    }
}

// ----------------------------------------------- classifier head (tiny)
__global__ void k_final(const float* __restrict__ pool, const float* __restrict__ cnt,
                        const float* __restrict__ Wc, const float* __restrict__ bc,
                        float* __restrict__ out) {
    int t = blockIdx.x * blockDim.x + threadIdx.x;
    if (t >= N_GRAPHS * N_CLASSES) return;
    int g = t / N_CLASSES, c = t % N_CLASSES;
    float inv = 1.0f / fmaxf(cnt[g], 1.0f);
    float acc = bc[c];
    for (int j = 0; j < HIDDEN; ++j)
        acc += pool[g * HIDDEN + j] * inv * Wc[j * N_CLASSES + c];
    out[t] = acc;
}

extern "C" void kernel_launch(void* const* d_in, const int* in_sizes, int n_in,
                              void* d_out, int out_size, void* d_ws, size_t ws_size,
                              hipStream_t stream) {
    const int*   src       = (const int*)d_in[0];
    const int*   dst       = (const int*)d_in[1];
    const int*   graph_ids = (const int*)d_in[2];
    const float* W1        = (const float*)d_in[3];
    const float* b1        = (const float*)d_in[4];
    const float* W2        = (const float*)d_in[5];
    const float* b2        = (const float*)d_in[6];
    const float* Wc        = (const float*)d_in[7];
    const float* bc        = (const float*)d_in[8];
    float* out = (float*)d_out;

    char* ws = (char*)d_ws;
    size_t off = 0;
    auto alloc = [&](size_t elems) { void* p = ws + off; off += elems * 4; return p; };

    // --- zeroed region (one tiny memset, 16B-multiple) ---
    unsigned* bcur1 = (unsigned*)alloc(256);
    unsigned* bcur2 = (unsigned*)alloc(256);
    float*    pool  = (float*)   alloc(N_GRAPHS * HIDDEN);
    float*    cnt   = (float*)   alloc(N_GRAPHS);
    size_t zero_bytes = off;
    // --- non-zeroed ---
    float4*   info  = (float4*)  alloc((size_t)N_NODES * 4);        // 1.6 MB
    unsigned* tmp1  = (unsigned*)alloc((size_t)NBUCK * CAP);        // 12.8 MB
    ushort*   tmp2  = (ushort*)  alloc((size_t)NBUCK * CAP / 2);    // 6.4 MB
    int*      csr   = (int*)     alloc((size_t)NBUCK * CAP);        // 12.8 MB
    unsigned* rsind = (unsigned*)alloc(N_NODES);
    float*    nsA   = (float*)   alloc(N_NODES);
    float*    hs0   = (float*)   alloc(N_NODES);
    float*    U     = (float*)   alloc(129 * HIDDEN);
    float*    V     = (float*)   alloc(129 * HIDDEN);

    hipMemsetAsync(d_ws, 0, zero_bytes, stream);

    int pblocks  = (N_EDGES + PCH - 1) / PCH;    // 391
    int c1blocks = (N_NODES + 127) / 128;        // 782
    int c2blocks = (N_NODES + 63) / 64;          // 1563
    k_part      <<<pblocks, PTH, 0, stream>>>(src, dst, bcur1, bcur2, tmp1, tmp2, N_EDGES);
    k_ind_csr   <<<NBUCK, 1024, 0, stream>>>(bcur1, tmp1, bcur2, tmp2, rsind, nsA, hs0, csr);
    k_conv1_info<<<c1blocks, 256, 0, stream>>>(rsind, csr, hs0, nsA, W1, b1, W2, U, V, info, N_NODES);
    k_conv2_pool<<<c2blocks, 256, 0, stream>>>(rsind, csr, info, U, V, graph_ids, b2, pool, cnt, N_NODES);
    k_final     <<<(N_GRAPHS * N_CLASSES + 255) / 256, 256, 0, stream>>>(pool, cnt, Wc, bc, out);
}